// Round 1
// baseline (146.206 us; speedup 1.0000x reference)
//
#include <hip/hip_runtime.h>
#include <math.h>

// Disable FP contraction globally: selection thresholds (iou >= 0.5) must be
// bit-exact vs the numpy float32 reference; FMA rewrites would perturb them.
#pragma clang fp contract(off)

#define BN   16      // batch
#define NP   2000    // proposals per batch
#define NG   200     // gt boxes per batch
#define NT   200     // output slots (T)
#define PMAX 66      // int(T * 0.33)
#define EPSF 1e-6f
#define MH   28
#define MW   28
#define HM   56      // input mask H=W

// ---------------------------------------------------------------------------
// Kernel A: per-proposal reductions over GTs.
// grid (ceil(NP/256), BN), block 256.
// Writes flag (0 none / 1 pos / 2 neg) and argmax-gt index per proposal.
// ---------------------------------------------------------------------------
__global__ __launch_bounds__(256) void kA(
    const float* __restrict__ proposals, const int* __restrict__ cls_ids,
    const float* __restrict__ boxes,
    int* __restrict__ flag_ws, int* __restrict__ assign_ws)
{
#pragma clang fp contract(off)
  const int b = blockIdx.y;
  __shared__ float4 gbox[NG];
  __shared__ float  garea[NG];
  __shared__ int    gflag[NG];   // 1 non-crowd, 2 crowd, 0 neither

  for (int j = threadIdx.x; j < NG; j += 256) {
    float4 g = reinterpret_cast<const float4*>(boxes + (size_t)b * NG * 4)[j];
    int c = cls_ids[b * NG + j];
    bool vg = (g.x != 0.f) || (g.y != 0.f) || (g.z != 0.f) || (g.w != 0.f);
    gbox[j]  = g;
    garea[j] = (g.z - g.x) * (g.w - g.y);
    gflag[j] = vg ? (c > 0 ? 1 : (c < 0 ? 2 : 0)) : 0;
  }
  __syncthreads();

  int i = blockIdx.x * 256 + threadIdx.x;
  if (i >= NP) return;

  float4 p = reinterpret_cast<const float4*>(proposals + (size_t)b * NP * 4)[i];
  bool vp = (p.x != 0.f) || (p.y != 0.f) || (p.z != 0.f) || (p.w != 0.f);
  float pa = (p.z - p.x) * (p.w - p.y);

  float best = -3.0e38f;   // first iteration always wins -> argmax-first
  int   bestj = 0;
  float cmax = 0.f;
  for (int j = 0; j < NG; ++j) {
    float4 g = gbox[j];
    // exact reference order: inter/(max(A+B-inter, eps))
    float iy = fmaxf(fminf(p.z, g.z) - fmaxf(p.x, g.x), 0.f);
    float ix = fmaxf(fminf(p.w, g.w) - fmaxf(p.y, g.y), 0.f);
    float inter = iy * ix;
    float uni = (pa + garea[j]) - inter;
    float iou = inter / fmaxf(uni, EPSF);
    int fl = gflag[j];
    float v = (fl == 1) ? iou : -1.0f;           // ov_nc
    if (v > best) { best = v; bestj = j; }       // strict > => first max
    if (fl == 2) cmax = fmaxf(cmax, iou);
  }
  bool pos = vp && (best >= 0.5f);
  bool neg = vp && (best < 0.5f) && (cmax < 0.001f);
  flag_ws[b * NP + i]   = pos ? 1 : (neg ? 2 : 0);
  assign_ws[b * NP + i] = bestj;
}

// ---------------------------------------------------------------------------
// Kernel B: stable compaction + slot assembly. grid BN, block 256.
// Writes rois/cls/deltas to d_out and per-slot mask metadata to ws.
// ---------------------------------------------------------------------------
__global__ __launch_bounds__(256) void kB(
    const float* __restrict__ proposals, const int* __restrict__ cls_ids,
    const float* __restrict__ boxes, const int* __restrict__ flag_ws,
    const int* __restrict__ assign_ws, float* __restrict__ out,
    float* __restrict__ mm_ws, int* __restrict__ ma_ws)
{
#pragma clang fp contract(off)
  const int b = blockIdx.x;
  const int tid = threadIdx.x;
  const int lane = tid & 63;
  const int wv = tid >> 6;

  __shared__ unsigned short pos_list[NP];
  __shared__ unsigned short neg_list[NP];
  __shared__ int wcp[4], wcn[4];
  __shared__ int s_pt, s_nt;
  if (tid == 0) { s_pt = 0; s_nt = 0; }
  __syncthreads();

  const int* fb = flag_ws + b * NP;
  // Stable (ascending-index) compaction == argsort of 0/1 keys.
  for (int base = 0; base < NP; base += 256) {
    int i = base + tid;
    int f = (i < NP) ? fb[i] : 0;
    bool isp = (f == 1), isn = (f == 2);
    unsigned long long bp = __ballot(isp);
    unsigned long long bn = __ballot(isn);
    __syncthreads();                               // protect wcp/wcn WAR
    if (lane == 0) { wcp[wv] = __popcll(bp); wcn[wv] = __popcll(bn); }
    __syncthreads();
    int prep = __popcll(bp & ((1ull << lane) - 1ull));
    int pren = __popcll(bn & ((1ull << lane) - 1ull));
    int bpp = 0, bnn = 0, tp = 0, tn = 0;
    for (int w = 0; w < 4; ++w) {
      if (w < wv) { bpp += wcp[w]; bnn += wcn[w]; }
      tp += wcp[w]; tn += wcn[w];
    }
    int pt = s_pt, nt = s_nt;
    if (isp) pos_list[pt + bpp + prep] = (unsigned short)i;
    if (isn) neg_list[nt + bnn + pren] = (unsigned short)i;
    __syncthreads();                               // lists done, s_* read done
    if (tid == 0) { s_pt = pt + tp; s_nt = nt + tn; }
  }
  __syncthreads();

  int pos_total = s_pt, neg_total = s_nt;
  int pos_count = min(pos_total, PMAX);
  int neg_needed = (int)floorf((float)pos_count / 0.33f) - pos_count;
  int neg_count = min(min(neg_needed, neg_total), NT - pos_count);

  if (tid < NT) {
    bool ispos = tid < pos_count;
    bool isneg = (!ispos) && (tid < pos_count + neg_count);
    float r0 = 0.f, r1 = 0.f, r2 = 0.f, r3 = 0.f;
    float d0 = 0.f, d1 = 0.f, d2 = 0.f, d3 = 0.f;
    float m0 = 0.f, m1 = 0.f, m2 = 0.f, m3 = 0.f;
    float clsf = 0.f;
    int ma = -1;
    if (ispos || isneg) {
      int i = ispos ? (int)pos_list[tid] : (int)neg_list[tid - pos_count];
      float4 p = reinterpret_cast<const float4*>(proposals + (size_t)b * NP * 4)[i];
      r0 = p.x; r1 = p.y; r2 = p.z; r3 = p.w;
      if (ispos) {
        int a = assign_ws[b * NP + i];
        ma = a;
        float4 g = reinterpret_cast<const float4*>(boxes + (size_t)b * NG * 4)[a];
        float h  = fmaxf(r2 - r0, EPSF);
        float w  = fmaxf(r3 - r1, EPSF);
        float cy = r0 + 0.5f * h;
        float cx = r1 + 0.5f * w;
        float gh = fmaxf(g.z - g.x, EPSF);
        float gw = fmaxf(g.w - g.y, EPSF);
        float gcy = g.x + 0.5f * gh;
        float gcx = g.y + 0.5f * gw;
        d0 = ((gcy - cy) / h) / 0.1f;
        d1 = ((gcx - cx) / w) / 0.1f;
        d2 = logf(gh / h) / 0.2f;
        d3 = logf(gw / w) / 0.2f;
        m0 = (r0 - g.x) / gh;
        m1 = (r1 - g.y) / gw;
        m2 = (r2 - g.x) / gh;
        m3 = (r3 - g.y) / gw;
        clsf = (float)cls_ids[b * NG + a];
      }
    }
    int s = b * NT + tid;
    float* rois = out;                         // [BN*NT*4]
    float* cls  = out + BN * NT * 4;           // [BN*NT]
    float* dlt  = out + BN * NT * 4 + BN * NT; // [BN*NT*4]
    rois[s * 4 + 0] = r0; rois[s * 4 + 1] = r1;
    rois[s * 4 + 2] = r2; rois[s * 4 + 3] = r3;
    cls[s] = clsf;
    dlt[s * 4 + 0] = d0; dlt[s * 4 + 1] = d1;
    dlt[s * 4 + 2] = d2; dlt[s * 4 + 3] = d3;
    mm_ws[s * 4 + 0] = m0; mm_ws[s * 4 + 1] = m1;
    mm_ws[s * 4 + 2] = m2; mm_ws[s * 4 + 3] = m3;
    ma_ws[s] = ma;
  }
}

// ---------------------------------------------------------------------------
// Kernel C: bilinear crop-resize of assigned GT mask. grid BN*NT, block 256.
// ---------------------------------------------------------------------------
__global__ __launch_bounds__(256) void kC(
    const float* __restrict__ masks, const float* __restrict__ mm_ws,
    const int* __restrict__ ma_ws, float* __restrict__ out)
{
#pragma clang fp contract(off)
  const int s = blockIdx.x;                    // b*NT + t
  float* om = out + (size_t)(BN * NT * 4 + BN * NT + BN * NT * 4)
                  + (size_t)s * (MH * MW);
  int a = ma_ws[s];
  if (a < 0) {
    for (int px = threadIdx.x; px < MH * MW; px += 256) om[px] = 0.f;
    return;
  }
  const int b = s / NT;
  float y1 = mm_ws[s * 4 + 0], x1 = mm_ws[s * 4 + 1];
  float y2 = mm_ws[s * 4 + 2], x2 = mm_ws[s * 4 + 3];
  // reference order: (y2-y1)*(H-1)/(MH-1)
  float sy = (y2 - y1) * 55.0f / 27.0f;
  float sx = (x2 - x1) * 55.0f / 27.0f;
  const float* mb = masks + (size_t)b * HM * HM * NG + a;  // [y][x] stride NG
  for (int px = threadIdx.x; px < MH * MW; px += 256) {
    int my = px / MW, mx = px % MW;
    float ys = y1 * 55.0f + (float)my * sy;
    float xs = x1 * 55.0f + (float)mx * sx;
    float y0f = floorf(ys), x0f = floorf(xs);
    float wy = ys - y0f, wx = xs - x0f;
    int y0i = (int)fminf(fmaxf(y0f, 0.f), 55.f);
    int y1i = (int)fminf(fmaxf(y0f + 1.0f, 0.f), 55.f);
    int x0i = (int)fminf(fmaxf(x0f, 0.f), 55.f);
    int x1i = (int)fminf(fmaxf(x0f + 1.0f, 0.f), 55.f);
    float v00 = mb[(y0i * HM + x0i) * NG];
    float v01 = mb[(y0i * HM + x1i) * NG];
    float v10 = mb[(y1i * HM + x0i) * NG];
    float v11 = mb[(y1i * HM + x1i) * NG];
    float val = (v00 * (1.f - wx) + v01 * wx) * (1.f - wy)
              + (v10 * (1.f - wx) + v11 * wx) * wy;
    bool ok = (ys >= 0.f) && (ys <= 55.f) && (xs >= 0.f) && (xs <= 55.f);
    om[px] = ok ? rintf(val) : 0.f;   // rintf = ties-to-even = np.round
  }
}

// ---------------------------------------------------------------------------
extern "C" void kernel_launch(void* const* d_in, const int* in_sizes, int n_in,
                              void* d_out, int out_size, void* d_ws, size_t ws_size,
                              hipStream_t stream)
{
  const float* proposals = (const float*)d_in[0];   // (16,2000,4)
  const int*   cls_ids   = (const int*)d_in[1];     // (16,200)
  const float* boxes     = (const float*)d_in[2];   // (16,200,4)
  const float* masks     = (const float*)d_in[3];   // (16,56,56,200)
  float* out = (float*)d_out;

  char* ws = (char*)d_ws;
  int*   flag_ws   = (int*)ws;    ws += (size_t)BN * NP * sizeof(int);
  int*   assign_ws = (int*)ws;    ws += (size_t)BN * NP * sizeof(int);
  float* mm_ws     = (float*)ws;  ws += (size_t)BN * NT * 4 * sizeof(float);
  int*   ma_ws     = (int*)ws;    ws += (size_t)BN * NT * sizeof(int);

  dim3 gA((NP + 255) / 256, BN);
  kA<<<gA, 256, 0, stream>>>(proposals, cls_ids, boxes, flag_ws, assign_ws);
  kB<<<BN, 256, 0, stream>>>(proposals, cls_ids, boxes, flag_ws, assign_ws,
                             out, mm_ws, ma_ws);
  kC<<<BN * NT, 256, 0, stream>>>(masks, mm_ws, ma_ws, out);
}

// Round 2
// 129.443 us; speedup vs baseline: 1.1295x; 1.1295x over previous
//
#include <hip/hip_runtime.h>
#include <math.h>

// Disable FP contraction globally: selection thresholds (iou >= 0.5) must be
// bit-exact vs the numpy float32 reference; FMA rewrites would perturb them.
#pragma clang fp contract(off)

#define BN    16      // batch
#define NP    2000    // proposals per batch
#define NG    200     // gt boxes per batch
#define NT    200     // output slots (T)
#define PMAX  66      // int(T * 0.33)
#define EPSF  1e-6f
#define MH    28
#define MW    28
#define HM    56      // input mask H=W
#define NPIX  (HM*HM) // 3136
#define NSLOT 128     // staged slots per batch (pos_count <= 66)

// ---------------------------------------------------------------------------
// Kernel A: per-proposal reductions over GTs.
// grid (ceil(NP/256), BN), block 256.
// ---------------------------------------------------------------------------
__global__ __launch_bounds__(256) void kA(
    const float* __restrict__ proposals, const int* __restrict__ cls_ids,
    const float* __restrict__ boxes,
    int* __restrict__ flag_ws, int* __restrict__ assign_ws)
{
#pragma clang fp contract(off)
  const int b = blockIdx.y;
  __shared__ float4 gbox[NG];
  __shared__ float  garea[NG];
  __shared__ int    gflag[NG];   // 1 non-crowd, 2 crowd, 0 neither

  for (int j = threadIdx.x; j < NG; j += 256) {
    float4 g = reinterpret_cast<const float4*>(boxes + (size_t)b * NG * 4)[j];
    int c = cls_ids[b * NG + j];
    bool vg = (g.x != 0.f) || (g.y != 0.f) || (g.z != 0.f) || (g.w != 0.f);
    gbox[j]  = g;
    garea[j] = (g.z - g.x) * (g.w - g.y);
    gflag[j] = vg ? (c > 0 ? 1 : (c < 0 ? 2 : 0)) : 0;
  }
  __syncthreads();

  int i = blockIdx.x * 256 + threadIdx.x;
  if (i >= NP) return;

  float4 p = reinterpret_cast<const float4*>(proposals + (size_t)b * NP * 4)[i];
  bool vp = (p.x != 0.f) || (p.y != 0.f) || (p.z != 0.f) || (p.w != 0.f);
  float pa = (p.z - p.x) * (p.w - p.y);

  float best = -3.0e38f;   // first iteration always wins -> argmax-first
  int   bestj = 0;
  float cmax = 0.f;
  for (int j = 0; j < NG; ++j) {
    float4 g = gbox[j];
    float iy = fmaxf(fminf(p.z, g.z) - fmaxf(p.x, g.x), 0.f);
    float ix = fmaxf(fminf(p.w, g.w) - fmaxf(p.y, g.y), 0.f);
    float inter = iy * ix;
    float uni = (pa + garea[j]) - inter;
    float iou = inter / fmaxf(uni, EPSF);
    int fl = gflag[j];
    float v = (fl == 1) ? iou : -1.0f;           // ov_nc
    if (v > best) { best = v; bestj = j; }       // strict > => first max
    if (fl == 2) cmax = fmaxf(cmax, iou);
  }
  bool pos = vp && (best >= 0.5f);
  bool neg = vp && (best < 0.5f) && (cmax < 0.001f);
  flag_ws[b * NP + i]   = pos ? 1 : (neg ? 2 : 0);
  assign_ws[b * NP + i] = bestj;
}

// ---------------------------------------------------------------------------
// Kernel B: stable compaction + slot assembly. grid BN, block 256.
// ---------------------------------------------------------------------------
__global__ __launch_bounds__(256) void kB(
    const float* __restrict__ proposals, const int* __restrict__ cls_ids,
    const float* __restrict__ boxes, const int* __restrict__ flag_ws,
    const int* __restrict__ assign_ws, float* __restrict__ out,
    float* __restrict__ mm_ws, int* __restrict__ ma_ws)
{
#pragma clang fp contract(off)
  const int b = blockIdx.x;
  const int tid = threadIdx.x;
  const int lane = tid & 63;
  const int wv = tid >> 6;

  __shared__ unsigned short pos_list[NP];
  __shared__ unsigned short neg_list[NP];
  __shared__ int wcp[4], wcn[4];
  __shared__ int s_pt, s_nt;
  if (tid == 0) { s_pt = 0; s_nt = 0; }
  __syncthreads();

  const int* fb = flag_ws + b * NP;
  for (int base = 0; base < NP; base += 256) {
    int i = base + tid;
    int f = (i < NP) ? fb[i] : 0;
    bool isp = (f == 1), isn = (f == 2);
    unsigned long long bp = __ballot(isp);
    unsigned long long bn = __ballot(isn);
    __syncthreads();
    if (lane == 0) { wcp[wv] = __popcll(bp); wcn[wv] = __popcll(bn); }
    __syncthreads();
    int prep = __popcll(bp & ((1ull << lane) - 1ull));
    int pren = __popcll(bn & ((1ull << lane) - 1ull));
    int bpp = 0, bnn = 0, tp = 0, tn = 0;
    for (int w = 0; w < 4; ++w) {
      if (w < wv) { bpp += wcp[w]; bnn += wcn[w]; }
      tp += wcp[w]; tn += wcn[w];
    }
    int pt = s_pt, nt = s_nt;
    if (isp) pos_list[pt + bpp + prep] = (unsigned short)i;
    if (isn) neg_list[nt + bnn + pren] = (unsigned short)i;
    __syncthreads();
    if (tid == 0) { s_pt = pt + tp; s_nt = nt + tn; }
  }
  __syncthreads();

  int pos_total = s_pt, neg_total = s_nt;
  int pos_count = min(pos_total, PMAX);
  int neg_needed = (int)floorf((float)pos_count / 0.33f) - pos_count;
  int neg_count = min(min(neg_needed, neg_total), NT - pos_count);

  if (tid < NT) {
    bool ispos = tid < pos_count;
    bool isneg = (!ispos) && (tid < pos_count + neg_count);
    float r0 = 0.f, r1 = 0.f, r2 = 0.f, r3 = 0.f;
    float d0 = 0.f, d1 = 0.f, d2 = 0.f, d3 = 0.f;
    float m0 = 0.f, m1 = 0.f, m2 = 0.f, m3 = 0.f;
    float clsf = 0.f;
    int ma = -1;
    if (ispos || isneg) {
      int i = ispos ? (int)pos_list[tid] : (int)neg_list[tid - pos_count];
      float4 p = reinterpret_cast<const float4*>(proposals + (size_t)b * NP * 4)[i];
      r0 = p.x; r1 = p.y; r2 = p.z; r3 = p.w;
      if (ispos) {
        int a = assign_ws[b * NP + i];
        ma = a;
        float4 g = reinterpret_cast<const float4*>(boxes + (size_t)b * NG * 4)[a];
        float h  = fmaxf(r2 - r0, EPSF);
        float w  = fmaxf(r3 - r1, EPSF);
        float cy = r0 + 0.5f * h;
        float cx = r1 + 0.5f * w;
        float gh = fmaxf(g.z - g.x, EPSF);
        float gw = fmaxf(g.w - g.y, EPSF);
        float gcy = g.x + 0.5f * gh;
        float gcx = g.y + 0.5f * gw;
        d0 = ((gcy - cy) / h) / 0.1f;
        d1 = ((gcx - cx) / w) / 0.1f;
        d2 = logf(gh / h) / 0.2f;
        d3 = logf(gw / w) / 0.2f;
        m0 = (r0 - g.x) / gh;
        m1 = (r1 - g.y) / gw;
        m2 = (r2 - g.x) / gh;
        m3 = (r3 - g.y) / gw;
        clsf = (float)cls_ids[b * NG + a];
      }
    }
    int s = b * NT + tid;
    float* rois = out;                         // [BN*NT*4]
    float* cls  = out + BN * NT * 4;           // [BN*NT]
    float* dlt  = out + BN * NT * 4 + BN * NT; // [BN*NT*4]
    rois[s * 4 + 0] = r0; rois[s * 4 + 1] = r1;
    rois[s * 4 + 2] = r2; rois[s * 4 + 3] = r3;
    cls[s] = clsf;
    dlt[s * 4 + 0] = d0; dlt[s * 4 + 1] = d1;
    dlt[s * 4 + 2] = d2; dlt[s * 4 + 3] = d3;
    mm_ws[s * 4 + 0] = m0; mm_ws[s * 4 + 1] = m1;
    mm_ws[s * 4 + 2] = m2; mm_ws[s * 4 + 3] = m3;
    ma_ws[s] = ma;
  }
}

// ---------------------------------------------------------------------------
// Kernel G: gather-transpose assigned masks into contiguous per-slot planes.
// grid (NPIX/64=49, NSLOT/64=2, BN), block 256.
// Read: lanes span slots -> for a fixed pixel the 64 gathered g-values live
// in one 800 B row (masks[b][p][0..200)) => ~7 useful 128 B lines/pixel.
// Write: lanes span pixels -> fully coalesced.
// ---------------------------------------------------------------------------
__global__ __launch_bounds__(256) void kG(
    const float* __restrict__ masks, const int* __restrict__ ma_ws,
    float* __restrict__ staged)
{
  const int b  = blockIdx.z;
  const int s0 = blockIdx.y * 64;
  const int p0 = blockIdx.x * 64;
  __shared__ float tile[64][65];   // [slot][pixel], pad -> 2-way alias (free)
  __shared__ int   sma[64];
  const int tid = threadIdx.x;
  if (tid < 64) sma[tid] = ma_ws[b * NT + s0 + tid];
  __syncthreads();

  const float* mbase = masks + (size_t)b * NPIX * NG;
  // read phase: lane = slot, pixel fixed per 64-lane group
  for (int e = 0; e < 16; ++e) {
    int idx = e * 256 + tid;
    int sl  = idx & 63;
    int pl  = idx >> 6;        // 0..63 across e
    int g   = sma[sl];
    float v = 0.f;
    if (g >= 0) v = mbase[(size_t)(p0 + pl) * NG + g];
    tile[sl][pl] = v;
  }
  __syncthreads();
  // write phase: lane = pixel
  for (int e = 0; e < 16; ++e) {
    int idx = e * 256 + tid;
    int pl  = idx & 63;
    int sl  = idx >> 6;
    if (sma[sl] >= 0)
      staged[(size_t)(b * NSLOT + s0 + sl) * NPIX + (p0 + pl)] = tile[sl][pl];
  }
}

// ---------------------------------------------------------------------------
// Kernel C: bilinear crop-resize from staged planes. grid BN*NT, block 256.
// Each active thread computes 4 consecutive pixels (28 % 4 == 0 -> same row),
// stores float4.
// ---------------------------------------------------------------------------
__global__ __launch_bounds__(256) void kC(
    const float* __restrict__ staged, const float* __restrict__ mm_ws,
    const int* __restrict__ ma_ws, float* __restrict__ out)
{
#pragma clang fp contract(off)
  const int s = blockIdx.x;                    // b*NT + t
  float4* om = reinterpret_cast<float4*>(
      out + (size_t)(BN * NT * 9) + (size_t)s * (MH * MW));
  const int q = threadIdx.x;                   // float4 index, 196 active
  if (q >= (MH * MW) / 4) return;
  int a = ma_ws[s];
  if (a < 0) { om[q] = make_float4(0.f, 0.f, 0.f, 0.f); return; }

  const int b = s / NT;
  const int t = s - b * NT;
  float y1 = mm_ws[s * 4 + 0], x1 = mm_ws[s * 4 + 1];
  float y2 = mm_ws[s * 4 + 2], x2 = mm_ws[s * 4 + 3];
  float sy = (y2 - y1) * 55.0f / 27.0f;        // reference order
  float sx = (x2 - x1) * 55.0f / 27.0f;
  const float* mp = staged + (size_t)(b * NSLOT + t) * NPIX;

  int px0 = q * 4;
  int my  = px0 / MW;                          // same row for all 4
  float ys = y1 * 55.0f + (float)my * sy;
  float y0f = floorf(ys);
  float wy  = ys - y0f;
  int y0i = (int)fminf(fmaxf(y0f, 0.f), 55.f);
  int y1i = (int)fminf(fmaxf(y0f + 1.0f, 0.f), 55.f);
  bool oky = (ys >= 0.f) && (ys <= 55.f);
  const float* r0 = mp + y0i * HM;
  const float* r1 = mp + y1i * HM;

  float res[4];
  for (int k = 0; k < 4; ++k) {
    int mx = (px0 + k) - my * MW;
    float xs = x1 * 55.0f + (float)mx * sx;
    float x0f = floorf(xs);
    float wx  = xs - x0f;
    int x0i = (int)fminf(fmaxf(x0f, 0.f), 55.f);
    int x1i = (int)fminf(fmaxf(x0f + 1.0f, 0.f), 55.f);
    float v00 = r0[x0i], v01 = r0[x1i];
    float v10 = r1[x0i], v11 = r1[x1i];
    float val = (v00 * (1.f - wx) + v01 * wx) * (1.f - wy)
              + (v10 * (1.f - wx) + v11 * wx) * wy;
    bool ok = oky && (xs >= 0.f) && (xs <= 55.f);
    res[k] = ok ? rintf(val) : 0.f;            // rintf = ties-even = np.round
  }
  om[q] = make_float4(res[0], res[1], res[2], res[3]);
}

// ---------------------------------------------------------------------------
extern "C" void kernel_launch(void* const* d_in, const int* in_sizes, int n_in,
                              void* d_out, int out_size, void* d_ws, size_t ws_size,
                              hipStream_t stream)
{
  const float* proposals = (const float*)d_in[0];   // (16,2000,4)
  const int*   cls_ids   = (const int*)d_in[1];     // (16,200)
  const float* boxes     = (const float*)d_in[2];   // (16,200,4)
  const float* masks     = (const float*)d_in[3];   // (16,56,56,200)
  float* out = (float*)d_out;

  char* ws = (char*)d_ws;
  int*   flag_ws   = (int*)ws;    ws += (size_t)BN * NP * sizeof(int);
  int*   assign_ws = (int*)ws;    ws += (size_t)BN * NP * sizeof(int);
  float* mm_ws     = (float*)ws;  ws += (size_t)BN * NT * 4 * sizeof(float);
  int*   ma_ws     = (int*)ws;    ws += (size_t)BN * NT * sizeof(int);
  float* staged    = (float*)ws;  // BN*NSLOT*NPIX floats = 25.7 MB

  dim3 gA((NP + 255) / 256, BN);
  kA<<<gA, 256, 0, stream>>>(proposals, cls_ids, boxes, flag_ws, assign_ws);
  kB<<<BN, 256, 0, stream>>>(proposals, cls_ids, boxes, flag_ws, assign_ws,
                             out, mm_ws, ma_ws);
  dim3 gG(NPIX / 64, NSLOT / 64, BN);
  kG<<<gG, 256, 0, stream>>>(masks, ma_ws, staged);
  kC<<<BN * NT, 256, 0, stream>>>(staged, mm_ws, ma_ws, out);
}